// Round 5
// baseline (422.272 us; speedup 1.0000x reference)
//
#include <hip/hip_runtime.h>
#include <hip/hip_bf16.h>

#define NA 8192
#define NB 2048
#define DIM 192
#define NH 4
#define DKH 48
#define TA 16
#define TB 32
#define PREC 208                       // floats per partial record
#define SCALE 0.14433756729740643f     // 1/sqrt(48)
#define INVSCALE 6.928203230275509f    // sqrt(48)
#define NEGBIG 1e30f

typedef __bf16 bf16x8 __attribute__((ext_vector_type(8)));
typedef float f32x4 __attribute__((ext_vector_type(4)));

#define MFMA16(a, b, c) __builtin_amdgcn_mfma_f32_16x16x32_bf16(a, b, c, 0, 0, 0)

// reduce over lanes differing in bits 4,5 (the g dimension); replicated after
__device__ __forceinline__ float rmaxg(float v) {
  v = fmaxf(v, __shfl_xor(v, 16, 64));
  v = fmaxf(v, __shfl_xor(v, 32, 64));
  return v;
}
__device__ __forceinline__ float rsumg(float v) {
  v += __shfl_xor(v, 16, 64);
  v += __shfl_xor(v, 32, 64);
  return v;
}

// ---------------- mask dtype detection ----------------
// flag: 0 = int32 {0,1}, 1 = byte (bool8/int8), 2 = float32 {0.0,1.0}
__global__ void maskdetect_kernel(const unsigned int* __restrict__ mw, int* __restrict__ flag) {
  __shared__ int fl;
  if (threadIdx.x == 0) fl = 0;
  __syncthreads();
  for (int i = threadIdx.x; i < 1024; i += 256) {
    unsigned int v = mw[i];
    if (v == 0x3F800000u) atomicMax(&fl, 2);
    else if (v > 1u) atomicMax(&fl, 1);
  }
  __syncthreads();
  if (threadIdx.x == 0) *flag = fl;
}

// ---------------- Q/K/V projections -> bf16, MFMA-friendly layouts ----------------
__global__ __launch_bounds__(192) void proj_kernel(
    const float* __restrict__ a_z, const float* __restrict__ bv_z,
    const float* __restrict__ Wq, const float* __restrict__ Wk, const float* __restrict__ Wv,
    const float* __restrict__ bq, const float* __restrict__ bk, const float* __restrict__ bvb,
    __bf16* __restrict__ Qo, __bf16* __restrict__ Ko, __bf16* __restrict__ Vo)
{
  __shared__ float xs[8][DIM];
  int blk = blockIdx.x;
  const float* src; const float* W; const float* bias; int row0; int which;
  if (blk < 1024)      { src = a_z;  W = Wq; bias = bq;  row0 = blk * 8;          which = 0; }
  else if (blk < 1280) { src = bv_z; W = Wk; bias = bk;  row0 = (blk - 1024) * 8; which = 1; }
  else                 { src = bv_z; W = Wv; bias = bvb; row0 = (blk - 1280) * 8; which = 2; }
  int t = threadIdx.x;
  for (int i = t; i < 8 * 48; i += 192) {
    int r = i / 48, c = i % 48;
    ((float4*)xs[r])[c] = ((const float4*)(src + (size_t)(row0 + r) * DIM))[c];
  }
  __syncthreads();
  float acc[8];
  float bb = bias[t];
  #pragma unroll
  for (int r = 0; r < 8; ++r) acc[r] = bb;
  const float4* wr = (const float4*)(W + (size_t)t * DIM);
  for (int c = 0; c < 48; ++c) {
    float4 w = wr[c];
    #pragma unroll
    for (int r = 0; r < 8; ++r) {
      float4 x = ((const float4*)xs[r])[c];
      acc[r] += w.x * x.x + w.y * x.y + w.z * x.z + w.w * x.w;
    }
  }
  int h = t / 48, dd = t % 48;
  if (which == 0) {
    #pragma unroll
    for (int r = 0; r < 8; ++r)
      Qo[((size_t)(row0 + r) * 4 + h) * 64 + dd] = (__bf16)acc[r];
    for (int i = t; i < 512; i += 192) {   // zero the K-pad [48,64)
      int r = i >> 6, hh = (i >> 4) & 3, kk = i & 15;
      Qo[((size_t)(row0 + r) * 4 + hh) * 64 + 48 + kk] = (__bf16)0.f;
    }
  } else if (which == 1) {
    #pragma unroll
    for (int r = 0; r < 8; ++r)
      Ko[((size_t)h * NB + row0 + r) * 64 + dd] = (__bf16)acc[r];
    for (int i = t; i < 512; i += 192) {
      int r = i >> 6, hh = (i >> 4) & 3, kk = i & 15;
      Ko[((size_t)hh * NB + row0 + r) * 64 + 48 + kk] = (__bf16)0.f;
    }
  } else {
    bf16x8 pk;
    #pragma unroll
    for (int r = 0; r < 8; ++r) pk[r] = (__bf16)acc[r];
    *(bf16x8*)(Vo + (size_t)t * NB + row0) = pk;   // transposed, 16B packed store
  }
}

// ---------------- Wo_eff^T ----------------
__global__ void woe_kernel(const float* __restrict__ Wo, const float* __restrict__ bo,
                           float* __restrict__ WoeT, float* __restrict__ boe)
{
  int i = blockIdx.x * 256 + threadIdx.x;
  if (i < DIM * DKH) {
    int k = i / DKH, d = i % DKH;
    float s = 0.25f * (Wo[(size_t)d * DIM + k] + Wo[(size_t)(d + 48) * DIM + k] +
                       Wo[(size_t)(d + 96) * DIM + k] + Wo[(size_t)(d + 144) * DIM + k]);
    WoeT[k * DKH + d] = s;
  }
  if (i < DKH) boe[i] = 0.25f * (bo[i] + bo[i + 48] + bo[i + 96] + bo[i + 144]);
}

// ---------------- VW = per-head V @ Woe_h (folds output projection into V) ----------------
__global__ __launch_bounds__(256) void vw_kernel(
    const __bf16* __restrict__ Vt, const float* __restrict__ WoeT, __bf16* __restrict__ VWt)
{
  __shared__ float woe[DIM][DKH];
  const int t = threadIdx.x;
  for (int i = t; i < DIM * DKH / 4; i += 256)
    ((float4*)&woe[0][0])[i] = ((const float4*)WoeT)[i];
  __syncthreads();
  const int b = blockIdx.x * 64 + (t & 63);
  const int h = t >> 6;
  float acc[DKH];
  #pragma unroll
  for (int d = 0; d < DKH; ++d) acc[d] = 0.f;
  for (int dp = 0; dp < DKH; ++dp) {
    float v = (float)Vt[(size_t)(h * DKH + dp) * NB + b];
    const float* wrow = woe[h * DKH + dp];
    #pragma unroll
    for (int d = 0; d < DKH; ++d) acc[d] += v * wrow[d];
  }
  #pragma unroll
  for (int d = 0; d < DKH; ++d)
    VWt[(size_t)(h * DKH + d) * NB + b] = (__bf16)acc[d];
}

// ---------------- fused MFMA attention (split-K partials) ----------------
// grid = ns * 512 blocks x 256 threads. Wave = head h.
// Swapped MFMA: S^T = K*Q^T (C col = actor = lane&15), T^T = VW^T * P^T.
// Depth-2 register prefetch of the weight/mask stream (the only HBM-cold data).
// No barrier in the main loop; one __syncthreads for the coalesced epilogue.
__global__ __launch_bounds__(256, 5) void attn_kernel(
    const __bf16* __restrict__ Qb, const __bf16* __restrict__ Kb, const __bf16* __restrict__ VWt,
    const float* __restrict__ weight, const void* __restrict__ maskp,
    const int* __restrict__ maskflag,
    float* __restrict__ part, int tps)
{
  __shared__ __bf16 Ss[4][16][40];              // per-wave P staging [a][b]
  __shared__ __align__(16) float Osf[16][212];  // epilogue staging (record = 208 f32)

  const int t = threadIdx.x;
  const int lane = t & 63;
  const int h = t >> 6;
  const int c = lane & 15;          // actor col
  const int g = lane >> 4;
  const int g8 = g * 8;
  const int s = blockIdx.x >> 9;    // split
  const int a0 = (blockIdx.x & 511) * TA;
  const int tile0 = s * tps;
  const int tend = tile0 + tps;

  const int mmode = *maskflag;
  const unsigned char* m8 = (const unsigned char*)maskp;

  // Q fragment (B-operand): col a = c, k contiguous
  const __bf16* qp = Qb + ((size_t)(a0 + c) * NH + h) * 64 + g8;
  const bf16x8 qf0 = *(const bf16x8*)qp;
  const bf16x8 qf1 = *(const bf16x8*)(qp + 32);

  float m = -NEGBIG, l = 0.f, A = 0.f, Mw = -NEGBIG, Lw = 0.f;
  f32x4 o0 = {0.f,0.f,0.f,0.f}, o1 = {0.f,0.f,0.f,0.f}, o2 = {0.f,0.f,0.f,0.f};

  const size_t wrow = (size_t)(a0 + c) * NB + g * 4;
  float wv[8];

#define ISSUE(T, W0, W1, MA, MB)                                                  \
  do {                                                                            \
    size_t gi = wrow + (size_t)(T) * TB;                                          \
    W0 = *(const float4*)(weight + gi);                                           \
    W1 = *(const float4*)(weight + gi + 16);                                      \
    if (mmode == 1)      { MA.x = *(const int*)(m8 + gi);                         \
                           MB.x = *(const int*)(m8 + gi + 16); }                  \
    else if (mmode == 2) { MA = *(const int4*)((const float*)maskp + gi);         \
                           MB = *(const int4*)((const float*)maskp + gi + 16); }  \
    else                 { MA = *(const int4*)((const int*)maskp + gi);           \
                           MB = *(const int4*)((const int*)maskp + gi + 16); }    \
  } while (0)

#define CONVERT(W0, W1, MA, MB)                                                   \
  do {                                                                            \
    if (mmode == 1) {                                                             \
      unsigned ua = (unsigned)MA.x, ub = (unsigned)MB.x;                          \
      wv[0] = (ua & 0xffu)         ? W0.x : -NEGBIG;                              \
      wv[1] = ((ua >> 8) & 0xffu)  ? W0.y : -NEGBIG;                              \
      wv[2] = ((ua >> 16) & 0xffu) ? W0.z : -NEGBIG;                              \
      wv[3] = (ua >> 24)           ? W0.w : -NEGBIG;                              \
      wv[4] = (ub & 0xffu)         ? W1.x : -NEGBIG;                              \
      wv[5] = ((ub >> 8) & 0xffu)  ? W1.y : -NEGBIG;                              \
      wv[6] = ((ub >> 16) & 0xffu) ? W1.z : -NEGBIG;                              \
      wv[7] = (ub >> 24)           ? W1.w : -NEGBIG;                              \
    } else if (mmode == 2) {                                                      \
      wv[0] = (((unsigned)MA.x << 1) != 0u) ? W0.x : -NEGBIG;                     \
      wv[1] = (((unsigned)MA.y << 1) != 0u) ? W0.y : -NEGBIG;                     \
      wv[2] = (((unsigned)MA.z << 1) != 0u) ? W0.z : -NEGBIG;                     \
      wv[3] = (((unsigned)MA.w << 1) != 0u) ? W0.w : -NEGBIG;                     \
      wv[4] = (((unsigned)MB.x << 1) != 0u) ? W1.x : -NEGBIG;                     \
      wv[5] = (((unsigned)MB.y << 1) != 0u) ? W1.y : -NEGBIG;                     \
      wv[6] = (((unsigned)MB.z << 1) != 0u) ? W1.z : -NEGBIG;                     \
      wv[7] = (((unsigned)MB.w << 1) != 0u) ? W1.w : -NEGBIG;                     \
    } else {                                                                      \
      wv[0] = MA.x ? W0.x : -NEGBIG;                                              \
      wv[1] = MA.y ? W0.y : -NEGBIG;                                              \
      wv[2] = MA.z ? W0.z : -NEGBIG;                                              \
      wv[3] = MA.w ? W0.w : -NEGBIG;                                              \
      wv[4] = MB.x ? W1.x : -NEGBIG;                                              \
      wv[5] = MB.y ? W1.y : -NEGBIG;                                              \
      wv[6] = MB.z ? W1.z : -NEGBIG;                                              \
      wv[7] = MB.w ? W1.w : -NEGBIG;                                              \
    }                                                                             \
  } while (0)

  auto body = [&](int tile) {
    const int b0 = tile * TB;
    // K fragments from global (L2-resident)
    const __bf16* kp = Kb + ((size_t)h * NB + b0 + c) * 64 + g8;
    bf16x8 kA0 = *(const bf16x8*)kp;
    bf16x8 kA1 = *(const bf16x8*)(kp + 32);
    bf16x8 kB0 = *(const bf16x8*)(kp + 16 * 64);
    bf16x8 kB1 = *(const bf16x8*)(kp + 16 * 64 + 32);
    // VW fragments issued early (consumed at PV)
    const __bf16* vp = VWt + ((size_t)(h * DKH + c)) * NB + b0 + g8;
    bf16x8 vf0 = *(const bf16x8*)vp;
    bf16x8 vf1 = *(const bf16x8*)(vp + 16 * NB);
    bf16x8 vf2 = *(const bf16x8*)(vp + 32 * NB);

    // S^T via MFMA, accumulator seeded with w/scale
    f32x4 acc0, acc1;
    #pragma unroll
    for (int j = 0; j < 4; ++j) { acc0[j] = wv[j] * INVSCALE; acc1[j] = wv[4 + j] * INVSCALE; }
    acc0 = MFMA16(kA0, qf0, acc0);
    acc0 = MFMA16(kA1, qf1, acc0);
    acc1 = MFMA16(kB0, qf0, acc1);
    acc1 = MFMA16(kB1, qf1, acc1);

    // weight-softmax running stats
    float wm = fmaxf(fmaxf(fmaxf(wv[0], wv[1]), fmaxf(wv[2], wv[3])),
                     fmaxf(fmaxf(wv[4], wv[5]), fmaxf(wv[6], wv[7])));
    wm = rmaxg(wm);
    float Mwn = fmaxf(Mw, wm);
    float awk = __expf(Mw - Mwn);
    float ew[8];
    #pragma unroll
    for (int i = 0; i < 8; ++i) ew[i] = __expf(wv[i] - Mwn);
    float ews = (ew[0] + ew[1]) + (ew[2] + ew[3]) + (ew[4] + ew[5]) + (ew[6] + ew[7]);
    Lw = Lw * awk + rsumg(ews);
    Mw = Mwn;

    // online softmax + joint influence accumulator
    float sv[8];
    #pragma unroll
    for (int j = 0; j < 4; ++j) { sv[j] = acc0[j] * SCALE; sv[4 + j] = acc1[j] * SCALE; }
    float mx = fmaxf(fmaxf(fmaxf(sv[0], sv[1]), fmaxf(sv[2], sv[3])),
                     fmaxf(fmaxf(sv[4], sv[5]), fmaxf(sv[6], sv[7])));
    float mn = fmaxf(m, rmaxg(mx));
    float al = __expf(m - mn);
    float p[8];
    #pragma unroll
    for (int i = 0; i < 8; ++i) p[i] = __expf(sv[i] - mn);
    float ls = (p[0] + p[1]) + (p[2] + p[3]) + (p[4] + p[5]) + (p[6] + p[7]);
    float as = (p[0] * ew[0] + p[1] * ew[1]) + (p[2] * ew[2] + p[3] * ew[3]) +
               (p[4] * ew[4] + p[5] * ew[5]) + (p[6] * ew[6] + p[7] * ew[7]);
    l = l * al + rsumg(ls);
    A = A * al * awk + rsumg(as);
    m = mn;
    #pragma unroll
    for (int j = 0; j < 4; ++j) { o0[j] *= al; o1[j] *= al; o2[j] *= al; }

    // P -> Ss (wave-private), read back as B-operand
    #pragma unroll
    for (int i = 0; i < 4; ++i) {
      Ss[h][c][g * 4 + i]      = (__bf16)p[i];
      Ss[h][c][16 + g * 4 + i] = (__bf16)p[4 + i];
    }
    __builtin_amdgcn_sched_barrier(0);
    bf16x8 pb = *(const bf16x8*)&Ss[h][c][g8];

    // T^T += VW^T * P^T
    o0 = MFMA16(vf0, pb, o0);
    o1 = MFMA16(vf1, pb, o1);
    o2 = MFMA16(vf2, pb, o2);
  };

  // depth-2 prefetch ring with named slots (tps is even: 16 or 32)
  float4 wa0, wa1, wb0, wb1;
  int4 maa, mab, mba, mbb;
  ISSUE(tile0, wa0, wa1, maa, mab);
  ISSUE(tile0 + 1, wb0, wb1, mba, mbb);
  for (int tile = tile0; tile < tend; tile += 2) {
    CONVERT(wa0, wa1, maa, mab);
    if (tile + 2 < tend) ISSUE(tile + 2, wa0, wa1, maa, mab);
    body(tile);
    CONVERT(wb0, wb1, mba, mbb);
    if (tile + 3 < tend) ISSUE(tile + 3, wb0, wb1, mba, mbb);
    body(tile + 1);
  }

  // ---- epilogue: stage record block in LDS, then fully-coalesced float4 copy ----
  if (t < 16) { Osf[t][206] = 0.f; Osf[t][207] = 0.f; }
  #pragma unroll
  for (int j = 0; j < 4; ++j) {
    Osf[c][h * 48 + g * 4 + j]      = o0[j];
    Osf[c][h * 48 + 16 + g * 4 + j] = o1[j];
    Osf[c][h * 48 + 32 + g * 4 + j] = o2[j];
  }
  if (g == 0) {
    Osf[c][192 + h] = m;
    Osf[c][196 + h] = l;
    Osf[c][200 + h] = A;
    if (h == 0) { Osf[c][204] = Mw; Osf[c][205] = Lw; }
  }
  __syncthreads();
  float* pr = part + ((size_t)s * NA + a0) * PREC;   // 16 contiguous records
  for (int i = t; i < 16 * (PREC / 4); i += 256) {
    int rec = i / (PREC / 4), off = i - rec * (PREC / 4);
    ((float4*)pr)[i] = ((const float4*)&Osf[rec][0])[off];
  }
#undef ISSUE
#undef CONVERT
}

// ---------------- merge splits: trivial scale-add (Woe already folded) ----------------
__global__ __launch_bounds__(256) void merge_kernel(
    const float* __restrict__ part, const float* __restrict__ boe,
    float* __restrict__ out, int ns)
{
  __shared__ float fls[32][NH][4];   // e^{m_s-m*}/l* per (a,h,s)
  __shared__ float infl[32][NH];
  const int t = threadIdx.x;
  const int a0 = blockIdx.x * 32;

  if (t < 128) {
    int a = t >> 2, hh = t & 3;
    const float* rec = part + (size_t)(a0 + a) * PREC;
    float mstar = -NEGBIG, Mwstar = -NEGBIG;
    for (int s = 0; s < ns; ++s) {
      const float* r = rec + (size_t)s * NA * PREC;
      mstar = fmaxf(mstar, r[192 + hh]);
      Mwstar = fmaxf(Mwstar, r[204]);
    }
    float lst = 0.f, Lws = 0.f, As = 0.f;
    for (int s = 0; s < ns; ++s) {
      const float* r = rec + (size_t)s * NA * PREC;
      float f = __expf(r[192 + hh] - mstar);
      float gg = __expf(r[204] - Mwstar);
      fls[a][hh][s] = f;
      lst += r[196 + hh] * f;
      As  += r[200 + hh] * f * gg;
      Lws += r[205] * gg;
    }
    float li = 1.f / lst;
    for (int s = 0; s < ns; ++s) fls[a][hh][s] *= li;
    infl[a][hh] = As * li / (4.f * Lws);
  }
  __syncthreads();
  if (t < 32)
    out[(size_t)(a0 + t) * 49 + 48] = infl[t][0] + infl[t][1] + infl[t][2] + infl[t][3];
  for (int i = t; i < 32 * DKH; i += 256) {
    int a = i / DKH, dd = i - a * DKH;
    float acc = boe[dd];
    const float* rec = part + (size_t)(a0 + a) * PREC;
    for (int s = 0; s < ns; ++s) {
      const float* r = rec + (size_t)s * NA * PREC;
      #pragma unroll
      for (int hh = 0; hh < NH; ++hh)
        acc += fls[a][hh][s] * r[hh * 48 + dd];
    }
    out[(size_t)(a0 + a) * 49 + dd] = acc;
  }
}

extern "C" void kernel_launch(void* const* d_in, const int* in_sizes, int n_in,
                              void* d_out, int out_size, void* d_ws, size_t ws_size,
                              hipStream_t stream) {
  const float* a_z    = (const float*)d_in[0];
  const float* bv_z   = (const float*)d_in[1];
  const float* weight = (const float*)d_in[2];
  const void*  maskp  = d_in[3];
  const float* Wq = (const float*)d_in[4];
  const float* Wk = (const float*)d_in[5];
  const float* Wv = (const float*)d_in[6];
  const float* Wo = (const float*)d_in[7];
  const float* bq = (const float*)d_in[8];
  const float* bk = (const float*)d_in[9];
  const float* bvb = (const float*)d_in[10];
  const float* bo = (const float*)d_in[11];

  __bf16* Qb  = (__bf16*)d_ws;                      // [NA][4][64]
  __bf16* Kb  = Qb + (size_t)NA * 256;              // [4][NB][64]
  __bf16* Vtg = Kb + (size_t)4 * NB * 64;           // [192][NB]
  __bf16* VWt = Vtg + (size_t)DIM * NB;             // [192][NB]
  float* WoeT = (float*)(VWt + (size_t)DIM * NB);   // [192][48]
  float* boe  = WoeT + DIM * DKH;
  int*  mflag = (int*)(boe + 64);
  float* part = (float*)(mflag + 64);               // [ns][NA][208]

  size_t base = (size_t)((char*)(part) - (char*)d_ws);
  int ns = (ws_size >= base + (size_t)4 * NA * PREC * 4) ? 4 : 2;
  int tps = (NB / TB) / ns;

  maskdetect_kernel<<<1, 256, 0, stream>>>((const unsigned int*)maskp, mflag);
  proj_kernel<<<1536, 192, 0, stream>>>(a_z, bv_z, Wq, Wk, Wv, bq, bk, bvb, Qb, Kb, Vtg);
  woe_kernel<<<36, 256, 0, stream>>>(Wo, bo, WoeT, boe);
  vw_kernel<<<NB / 64, 256, 0, stream>>>(Vtg, WoeT, VWt);
  attn_kernel<<<ns * 512, 256, 0, stream>>>(Qb, Kb, VWt, weight, maskp, mflag, part, tps);
  merge_kernel<<<NA / 32, 256, 0, stream>>>(part, boe, (float*)d_out, ns);
}

// Round 6
// 269.832 us; speedup vs baseline: 1.5649x; 1.5649x over previous
//
#include <hip/hip_runtime.h>
#include <hip/hip_bf16.h>

#define NA 8192
#define NB 2048
#define DIM 192
#define NH 4
#define DKH 48
#define TA 16
#define TB 32
#define PREC 208                       // floats per partial record
#define SCALE 0.14433756729740643f     // 1/sqrt(48)
#define INVSCALE 6.928203230275509f    // sqrt(48)
#define NEGBIG 1e30f

typedef __bf16 bf16x8 __attribute__((ext_vector_type(8)));
typedef float f32x4 __attribute__((ext_vector_type(4)));

#define MFMA16(a, b, c) __builtin_amdgcn_mfma_f32_16x16x32_bf16(a, b, c, 0, 0, 0)

// reduce over lanes differing in bits 4,5 (the g dimension); replicated after
__device__ __forceinline__ float rmaxg(float v) {
  v = fmaxf(v, __shfl_xor(v, 16, 64));
  v = fmaxf(v, __shfl_xor(v, 32, 64));
  return v;
}
__device__ __forceinline__ float rsumg(float v) {
  v += __shfl_xor(v, 16, 64);
  v += __shfl_xor(v, 32, 64);
  return v;
}

// ---------------- mask dtype detection ----------------
// flag: 0 = int32 {0,1}, 1 = byte (bool8/int8), 2 = float32 {0.0,1.0}
__global__ void maskdetect_kernel(const unsigned int* __restrict__ mw, int* __restrict__ flag) {
  __shared__ int fl;
  if (threadIdx.x == 0) fl = 0;
  __syncthreads();
  for (int i = threadIdx.x; i < 1024; i += 256) {
    unsigned int v = mw[i];
    if (v == 0x3F800000u) atomicMax(&fl, 2);
    else if (v > 1u) atomicMax(&fl, 1);
  }
  __syncthreads();
  if (threadIdx.x == 0) *flag = fl;
}

// ---------------- Q/K/V projections -> bf16, MFMA-friendly layouts ----------------
__global__ __launch_bounds__(192) void proj_kernel(
    const float* __restrict__ a_z, const float* __restrict__ bv_z,
    const float* __restrict__ Wq, const float* __restrict__ Wk, const float* __restrict__ Wv,
    const float* __restrict__ bq, const float* __restrict__ bk, const float* __restrict__ bvb,
    __bf16* __restrict__ Qo, __bf16* __restrict__ Ko, __bf16* __restrict__ Vo)
{
  __shared__ float xs[8][DIM];
  int blk = blockIdx.x;
  const float* src; const float* W; const float* bias; int row0; int which;
  if (blk < 1024)      { src = a_z;  W = Wq; bias = bq;  row0 = blk * 8;          which = 0; }
  else if (blk < 1280) { src = bv_z; W = Wk; bias = bk;  row0 = (blk - 1024) * 8; which = 1; }
  else                 { src = bv_z; W = Wv; bias = bvb; row0 = (blk - 1280) * 8; which = 2; }
  int t = threadIdx.x;
  for (int i = t; i < 8 * 48; i += 192) {
    int r = i / 48, c = i % 48;
    ((float4*)xs[r])[c] = ((const float4*)(src + (size_t)(row0 + r) * DIM))[c];
  }
  __syncthreads();
  float acc[8];
  float bb = bias[t];
  #pragma unroll
  for (int r = 0; r < 8; ++r) acc[r] = bb;
  const float4* wr = (const float4*)(W + (size_t)t * DIM);
  for (int c = 0; c < 48; ++c) {
    float4 w = wr[c];
    #pragma unroll
    for (int r = 0; r < 8; ++r) {
      float4 x = ((const float4*)xs[r])[c];
      acc[r] += w.x * x.x + w.y * x.y + w.z * x.z + w.w * x.w;
    }
  }
  int h = t / 48, dd = t % 48;
  if (which == 0) {
    #pragma unroll
    for (int r = 0; r < 8; ++r)
      Qo[((size_t)(row0 + r) * 4 + h) * 64 + dd] = (__bf16)acc[r];
    for (int i = t; i < 512; i += 192) {   // zero the K-pad [48,64)
      int r = i >> 6, hh = (i >> 4) & 3, kk = i & 15;
      Qo[((size_t)(row0 + r) * 4 + hh) * 64 + 48 + kk] = (__bf16)0.f;
    }
  } else if (which == 1) {
    #pragma unroll
    for (int r = 0; r < 8; ++r)
      Ko[((size_t)h * NB + row0 + r) * 64 + dd] = (__bf16)acc[r];
    for (int i = t; i < 512; i += 192) {
      int r = i >> 6, hh = (i >> 4) & 3, kk = i & 15;
      Ko[((size_t)hh * NB + row0 + r) * 64 + 48 + kk] = (__bf16)0.f;
    }
  } else {
    bf16x8 pk;
    #pragma unroll
    for (int r = 0; r < 8; ++r) pk[r] = (__bf16)acc[r];
    *(bf16x8*)(Vo + (size_t)t * NB + row0) = pk;   // transposed, 16B packed store
  }
}

// ---------------- Wo_eff^T ----------------
__global__ void woe_kernel(const float* __restrict__ Wo, const float* __restrict__ bo,
                           float* __restrict__ WoeT, float* __restrict__ boe)
{
  int i = blockIdx.x * 256 + threadIdx.x;
  if (i < DIM * DKH) {
    int k = i / DKH, d = i % DKH;
    float s = 0.25f * (Wo[(size_t)d * DIM + k] + Wo[(size_t)(d + 48) * DIM + k] +
                       Wo[(size_t)(d + 96) * DIM + k] + Wo[(size_t)(d + 144) * DIM + k]);
    WoeT[k * DKH + d] = s;
  }
  if (i < DKH) boe[i] = 0.25f * (bo[i] + bo[i + 48] + bo[i + 96] + bo[i + 144]);
}

// ---------------- VW = per-head V @ Woe_h (folds output projection into V) ----------------
__global__ __launch_bounds__(256) void vw_kernel(
    const __bf16* __restrict__ Vt, const float* __restrict__ WoeT, __bf16* __restrict__ VWt)
{
  __shared__ float woe[DIM][DKH];
  const int t = threadIdx.x;
  for (int i = t; i < DIM * DKH / 4; i += 256)
    ((float4*)&woe[0][0])[i] = ((const float4*)WoeT)[i];
  __syncthreads();
  const int b = blockIdx.x * 64 + (t & 63);
  const int h = t >> 6;
  float acc[DKH];
  #pragma unroll
  for (int d = 0; d < DKH; ++d) acc[d] = 0.f;
  for (int dp = 0; dp < DKH; ++dp) {
    float v = (float)Vt[(size_t)(h * DKH + dp) * NB + b];
    const float* wrow = woe[h * DKH + dp];
    #pragma unroll
    for (int d = 0; d < DKH; ++d) acc[d] += v * wrow[d];
  }
  #pragma unroll
  for (int d = 0; d < DKH; ++d)
    VWt[(size_t)(h * DKH + d) * NB + b] = (__bf16)acc[d];
}

// ---------------- fused MFMA attention (split-K partials) ----------------
// grid = ns * 512 blocks x 256 threads. Wave = head h.
// Swapped MFMA: S^T = K*Q^T (C col = actor = lane&15), T^T = VW^T * P^T.
// Lean depth-1 register prefetch of weight+mask (the only HBM-cold stream).
// No __syncthreads anywhere; P round-trip LDS is wave-private.
__global__ __launch_bounds__(256, 4) void attn_kernel(
    const __bf16* __restrict__ Qb, const __bf16* __restrict__ Kb, const __bf16* __restrict__ VWt,
    const float* __restrict__ weight, const void* __restrict__ maskp,
    const int* __restrict__ maskflag,
    float* __restrict__ part, int tps)
{
  __shared__ __bf16 Ss[4][16][40];   // per-wave P staging [a][b]

  const int t = threadIdx.x;
  const int lane = t & 63;
  const int h = t >> 6;
  const int c = lane & 15;          // actor col
  const int g = lane >> 4;
  const int g8 = g * 8;
  const int s = blockIdx.x >> 9;    // split
  const int a0 = (blockIdx.x & 511) * TA;
  const int tile0 = s * tps;
  const int tend = tile0 + tps;

  const int mmode = *maskflag;
  const unsigned char* m8 = (const unsigned char*)maskp;
  const float* mfp = (const float*)maskp;
  const int* m32 = (const int*)maskp;

  // Q fragment (B-operand): col a = c, k contiguous
  const __bf16* qp = Qb + ((size_t)(a0 + c) * NH + h) * 64 + g8;
  const bf16x8 qf0 = *(const bf16x8*)qp;
  const bf16x8 qf1 = *(const bf16x8*)(qp + 32);

  float m = -NEGBIG, l = 0.f, A = 0.f, Mw = -NEGBIG, Lw = 0.f;
  f32x4 o0 = {0.f,0.f,0.f,0.f}, o1 = {0.f,0.f,0.f,0.f}, o2 = {0.f,0.f,0.f,0.f};

  const size_t wrow = (size_t)(a0 + c) * NB + g * 4;

  // ---- preload tile0's weight+mask and convert ----
  float4 nw0, nw1;
  int4 nmA = {0,0,0,0}, nmB = {0,0,0,0};
  {
    size_t gi = wrow + (size_t)tile0 * TB;
    nw0 = *(const float4*)(weight + gi);
    nw1 = *(const float4*)(weight + gi + 16);
    if (mmode == 1)      { nmA.x = *(const int*)(m8 + gi); nmB.x = *(const int*)(m8 + gi + 16); }
    else if (mmode == 2) { nmA = *(const int4*)(mfp + gi); nmB = *(const int4*)(mfp + gi + 16); }
    else                 { nmA = *(const int4*)(m32 + gi); nmB = *(const int4*)(m32 + gi + 16); }
  }
  float wv[8];
  {
    if (mmode == 1) {
      unsigned ua = (unsigned)nmA.x, ub = (unsigned)nmB.x;
      wv[0] = (ua & 0xffu)         ? nw0.x : -NEGBIG;
      wv[1] = ((ua >> 8) & 0xffu)  ? nw0.y : -NEGBIG;
      wv[2] = ((ua >> 16) & 0xffu) ? nw0.z : -NEGBIG;
      wv[3] = (ua >> 24)           ? nw0.w : -NEGBIG;
      wv[4] = (ub & 0xffu)         ? nw1.x : -NEGBIG;
      wv[5] = ((ub >> 8) & 0xffu)  ? nw1.y : -NEGBIG;
      wv[6] = ((ub >> 16) & 0xffu) ? nw1.z : -NEGBIG;
      wv[7] = (ub >> 24)           ? nw1.w : -NEGBIG;
    } else if (mmode == 2) {
      wv[0] = (((unsigned)nmA.x << 1) != 0u) ? nw0.x : -NEGBIG;
      wv[1] = (((unsigned)nmA.y << 1) != 0u) ? nw0.y : -NEGBIG;
      wv[2] = (((unsigned)nmA.z << 1) != 0u) ? nw0.z : -NEGBIG;
      wv[3] = (((unsigned)nmA.w << 1) != 0u) ? nw0.w : -NEGBIG;
      wv[4] = (((unsigned)nmB.x << 1) != 0u) ? nw1.x : -NEGBIG;
      wv[5] = (((unsigned)nmB.y << 1) != 0u) ? nw1.y : -NEGBIG;
      wv[6] = (((unsigned)nmB.z << 1) != 0u) ? nw1.z : -NEGBIG;
      wv[7] = (((unsigned)nmB.w << 1) != 0u) ? nw1.w : -NEGBIG;
    } else {
      wv[0] = nmA.x ? nw0.x : -NEGBIG;
      wv[1] = nmA.y ? nw0.y : -NEGBIG;
      wv[2] = nmA.z ? nw0.z : -NEGBIG;
      wv[3] = nmA.w ? nw0.w : -NEGBIG;
      wv[4] = nmB.x ? nw1.x : -NEGBIG;
      wv[5] = nmB.y ? nw1.y : -NEGBIG;
      wv[6] = nmB.z ? nw1.z : -NEGBIG;
      wv[7] = nmB.w ? nw1.w : -NEGBIG;
    }
  }

  for (int tile = tile0; tile < tend; ++tile) {
    const int b0 = tile * TB;

    // 1. issue next tile's weight+mask loads (depth-1; land during this body)
    {
      int tn = (tile + 1 < tend) ? tile + 1 : tile;
      size_t gi = wrow + (size_t)tn * TB;
      nw0 = *(const float4*)(weight + gi);
      nw1 = *(const float4*)(weight + gi + 16);
      if (mmode == 1)      { nmA.x = *(const int*)(m8 + gi); nmB.x = *(const int*)(m8 + gi + 16); }
      else if (mmode == 2) { nmA = *(const int4*)(mfp + gi); nmB = *(const int4*)(mfp + gi + 16); }
      else                 { nmA = *(const int4*)(m32 + gi); nmB = *(const int4*)(m32 + gi + 16); }
    }

    // 2. K fragments from global (L2-resident)
    const __bf16* kp = Kb + ((size_t)h * NB + b0 + c) * 64 + g8;
    bf16x8 kA0 = *(const bf16x8*)kp;
    bf16x8 kA1 = *(const bf16x8*)(kp + 32);
    bf16x8 kB0 = *(const bf16x8*)(kp + 16 * 64);
    bf16x8 kB1 = *(const bf16x8*)(kp + 16 * 64 + 32);
    // 3. VW fragments issued early (consumed at PV)
    const __bf16* vp = VWt + ((size_t)(h * DKH + c)) * NB + b0 + g8;
    bf16x8 vf0 = *(const bf16x8*)vp;
    bf16x8 vf1 = *(const bf16x8*)(vp + 16 * NB);
    bf16x8 vf2 = *(const bf16x8*)(vp + 32 * NB);

    // 4. S^T via MFMA, accumulator seeded with w/scale
    f32x4 acc0, acc1;
    #pragma unroll
    for (int j = 0; j < 4; ++j) { acc0[j] = wv[j] * INVSCALE; acc1[j] = wv[4 + j] * INVSCALE; }
    acc0 = MFMA16(kA0, qf0, acc0);
    acc0 = MFMA16(kA1, qf1, acc0);
    acc1 = MFMA16(kB0, qf0, acc1);
    acc1 = MFMA16(kB1, qf1, acc1);

    // 5. weight-softmax running stats
    float wm = fmaxf(fmaxf(fmaxf(wv[0], wv[1]), fmaxf(wv[2], wv[3])),
                     fmaxf(fmaxf(wv[4], wv[5]), fmaxf(wv[6], wv[7])));
    wm = rmaxg(wm);
    float Mwn = fmaxf(Mw, wm);
    float awk = __expf(Mw - Mwn);
    float ew[8];
    #pragma unroll
    for (int i = 0; i < 8; ++i) ew[i] = __expf(wv[i] - Mwn);
    float ews = (ew[0] + ew[1]) + (ew[2] + ew[3]) + (ew[4] + ew[5]) + (ew[6] + ew[7]);
    Lw = Lw * awk + rsumg(ews);
    Mw = Mwn;

    // 6. online softmax + joint influence accumulator
    float sv[8];
    #pragma unroll
    for (int j = 0; j < 4; ++j) { sv[j] = acc0[j] * SCALE; sv[4 + j] = acc1[j] * SCALE; }
    float mx = fmaxf(fmaxf(fmaxf(sv[0], sv[1]), fmaxf(sv[2], sv[3])),
                     fmaxf(fmaxf(sv[4], sv[5]), fmaxf(sv[6], sv[7])));
    float mn = fmaxf(m, rmaxg(mx));
    float al = __expf(m - mn);
    float p[8];
    #pragma unroll
    for (int i = 0; i < 8; ++i) p[i] = __expf(sv[i] - mn);
    float ls = (p[0] + p[1]) + (p[2] + p[3]) + (p[4] + p[5]) + (p[6] + p[7]);
    float as = (p[0] * ew[0] + p[1] * ew[1]) + (p[2] * ew[2] + p[3] * ew[3]) +
               (p[4] * ew[4] + p[5] * ew[5]) + (p[6] * ew[6] + p[7] * ew[7]);
    l = l * al + rsumg(ls);
    A = A * al * awk + rsumg(as);
    m = mn;
    #pragma unroll
    for (int j = 0; j < 4; ++j) { o0[j] *= al; o1[j] *= al; o2[j] *= al; }

    // 7. P -> Ss (wave-private), read back as B-operand
    #pragma unroll
    for (int i = 0; i < 4; ++i) {
      Ss[h][c][g * 4 + i]      = (__bf16)p[i];
      Ss[h][c][16 + g * 4 + i] = (__bf16)p[4 + i];
    }
    __builtin_amdgcn_sched_barrier(0);
    bf16x8 pb = *(const bf16x8*)&Ss[h][c][g8];

    // 8. T^T += VW^T * P^T
    o0 = MFMA16(vf0, pb, o0);
    o1 = MFMA16(vf1, pb, o1);
    o2 = MFMA16(vf2, pb, o2);

    // 9. convert prefetched weight+mask for the next tile (loads landed by now)
    if (mmode == 1) {
      unsigned ua = (unsigned)nmA.x, ub = (unsigned)nmB.x;
      wv[0] = (ua & 0xffu)         ? nw0.x : -NEGBIG;
      wv[1] = ((ua >> 8) & 0xffu)  ? nw0.y : -NEGBIG;
      wv[2] = ((ua >> 16) & 0xffu) ? nw0.z : -NEGBIG;
      wv[3] = (ua >> 24)           ? nw0.w : -NEGBIG;
      wv[4] = (ub & 0xffu)         ? nw1.x : -NEGBIG;
      wv[5] = ((ub >> 8) & 0xffu)  ? nw1.y : -NEGBIG;
      wv[6] = ((ub >> 16) & 0xffu) ? nw1.z : -NEGBIG;
      wv[7] = (ub >> 24)           ? nw1.w : -NEGBIG;
    } else if (mmode == 2) {
      wv[0] = (((unsigned)nmA.x << 1) != 0u) ? nw0.x : -NEGBIG;
      wv[1] = (((unsigned)nmA.y << 1) != 0u) ? nw0.y : -NEGBIG;
      wv[2] = (((unsigned)nmA.z << 1) != 0u) ? nw0.z : -NEGBIG;
      wv[3] = (((unsigned)nmA.w << 1) != 0u) ? nw0.w : -NEGBIG;
      wv[4] = (((unsigned)nmB.x << 1) != 0u) ? nw1.x : -NEGBIG;
      wv[5] = (((unsigned)nmB.y << 1) != 0u) ? nw1.y : -NEGBIG;
      wv[6] = (((unsigned)nmB.z << 1) != 0u) ? nw1.z : -NEGBIG;
      wv[7] = (((unsigned)nmB.w << 1) != 0u) ? nw1.w : -NEGBIG;
    } else {
      wv[0] = nmA.x ? nw0.x : -NEGBIG;
      wv[1] = nmA.y ? nw0.y : -NEGBIG;
      wv[2] = nmA.z ? nw0.z : -NEGBIG;
      wv[3] = nmA.w ? nw0.w : -NEGBIG;
      wv[4] = nmB.x ? nw1.x : -NEGBIG;
      wv[5] = nmB.y ? nw1.y : -NEGBIG;
      wv[6] = nmB.z ? nw1.z : -NEGBIG;
      wv[7] = nmB.w ? nw1.w : -NEGBIG;
    }
  }

  // ---- write unnormalized partial record for (split s, actor a0+c) ----
  // (R3-proven clean: same-line stores merge in L2; WRITE_SIZE was exact)
  float* pr = part + ((size_t)s * NA + a0 + c) * PREC;
  #pragma unroll
  for (int j = 0; j < 4; ++j) {
    pr[h * 48 + g * 4 + j]      = o0[j];
    pr[h * 48 + 16 + g * 4 + j] = o1[j];
    pr[h * 48 + 32 + g * 4 + j] = o2[j];
  }
  if (g == 0) {
    pr[192 + h] = m;
    pr[196 + h] = l;
    pr[200 + h] = A;
    if (h == 0) { pr[204] = Mw; pr[205] = Lw; }
  }
}

// ---------------- merge splits: trivial scale-add (Woe already folded) ----------------
__global__ __launch_bounds__(256) void merge_kernel(
    const float* __restrict__ part, const float* __restrict__ boe,
    float* __restrict__ out, int ns)
{
  __shared__ float fls[32][NH][4];   // e^{m_s-m*}/l* per (a,h,s)
  __shared__ float infl[32][NH];
  const int t = threadIdx.x;
  const int a0 = blockIdx.x * 32;

  if (t < 128) {
    int a = t >> 2, hh = t & 3;
    const float* rec = part + (size_t)(a0 + a) * PREC;
    float mstar = -NEGBIG, Mwstar = -NEGBIG;
    for (int s = 0; s < ns; ++s) {
      const float* r = rec + (size_t)s * NA * PREC;
      mstar = fmaxf(mstar, r[192 + hh]);
      Mwstar = fmaxf(Mwstar, r[204]);
    }
    float lst = 0.f, Lws = 0.f, As = 0.f;
    for (int s = 0; s < ns; ++s) {
      const float* r = rec + (size_t)s * NA * PREC;
      float f = __expf(r[192 + hh] - mstar);
      float gg = __expf(r[204] - Mwstar);
      fls[a][hh][s] = f;
      lst += r[196 + hh] * f;
      As  += r[200 + hh] * f * gg;
      Lws += r[205] * gg;
    }
    float li = 1.f / lst;
    for (int s = 0; s < ns; ++s) fls[a][hh][s] *= li;
    infl[a][hh] = As * li / (4.f * Lws);
  }
  __syncthreads();
  if (t < 32)
    out[(size_t)(a0 + t) * 49 + 48] = infl[t][0] + infl[t][1] + infl[t][2] + infl[t][3];
  for (int i = t; i < 32 * DKH; i += 256) {
    int a = i / DKH, dd = i - a * DKH;
    float acc = boe[dd];
    const float* rec = part + (size_t)(a0 + a) * PREC;
    for (int s = 0; s < ns; ++s) {
      const float* r = rec + (size_t)s * NA * PREC;
      #pragma unroll
      for (int hh = 0; hh < NH; ++hh)
        acc += fls[a][hh][s] * r[hh * 48 + dd];
    }
    out[(size_t)(a0 + a) * 49 + dd] = acc;
  }
}

extern "C" void kernel_launch(void* const* d_in, const int* in_sizes, int n_in,
                              void* d_out, int out_size, void* d_ws, size_t ws_size,
                              hipStream_t stream) {
  const float* a_z    = (const float*)d_in[0];
  const float* bv_z   = (const float*)d_in[1];
  const float* weight = (const float*)d_in[2];
  const void*  maskp  = d_in[3];
  const float* Wq = (const float*)d_in[4];
  const float* Wk = (const float*)d_in[5];
  const float* Wv = (const float*)d_in[6];
  const float* Wo = (const float*)d_in[7];
  const float* bq = (const float*)d_in[8];
  const float* bk = (const float*)d_in[9];
  const float* bvb = (const float*)d_in[10];
  const float* bo = (const float*)d_in[11];

  __bf16* Qb  = (__bf16*)d_ws;                      // [NA][4][64]
  __bf16* Kb  = Qb + (size_t)NA * 256;              // [4][NB][64]
  __bf16* Vtg = Kb + (size_t)4 * NB * 64;           // [192][NB]
  __bf16* VWt = Vtg + (size_t)DIM * NB;             // [192][NB]
  float* WoeT = (float*)(VWt + (size_t)DIM * NB);   // [192][48]
  float* boe  = WoeT + DIM * DKH;
  int*  mflag = (int*)(boe + 64);
  float* part = (float*)(mflag + 64);               // [ns][NA][208]

  size_t base = (size_t)((char*)(part) - (char*)d_ws);
  int ns = (ws_size >= base + (size_t)4 * NA * PREC * 4) ? 4 : 2;
  int tps = (NB / TB) / ns;

  maskdetect_kernel<<<1, 256, 0, stream>>>((const unsigned int*)maskp, mflag);
  proj_kernel<<<1536, 192, 0, stream>>>(a_z, bv_z, Wq, Wk, Wv, bq, bk, bvb, Qb, Kb, Vtg);
  woe_kernel<<<36, 256, 0, stream>>>(Wo, bo, WoeT, boe);
  vw_kernel<<<NB / 64, 256, 0, stream>>>(Vtg, WoeT, VWt);
  attn_kernel<<<ns * 512, 256, 0, stream>>>(Qb, Kb, VWt, weight, maskp, mflag, part, tps);
  merge_kernel<<<NA / 32, 256, 0, stream>>>(part, boe, (float*)d_out, ns);
}